// Round 6
// baseline (7390.998 us; speedup 1.0000x reference)
//
#include <hip/hip_runtime.h>
#include <cstdint>
#include <cstddef>

#define SS   512
#define BB   64
#define EMBD 768
#define HIDN 512
#define G4   2048
#define NTAG 9

typedef __attribute__((ext_vector_type(8))) __bf16 bf16x8;
typedef __attribute__((ext_vector_type(4))) float  f32x4;
typedef unsigned long long u64;

union HCast { f32x4 f; bf16x8 h; };

// ---- device-scope (coherence-point) bypass ops: sc0 sc1 --------------------
__device__ inline void load_h4_bypass(const void* base, f32x4* f) {
  asm volatile(
    "global_load_dwordx4 %0, %4, off sc0 sc1\n\t"
    "global_load_dwordx4 %1, %4, off offset:64 sc0 sc1\n\t"
    "global_load_dwordx4 %2, %4, off offset:128 sc0 sc1\n\t"
    "global_load_dwordx4 %3, %4, off offset:192 sc0 sc1\n\t"
    "s_waitcnt vmcnt(0)"
    : "=&v"(f[0]), "=&v"(f[1]), "=&v"(f[2]), "=&v"(f[3])
    : "v"(base) : "memory");
}
__device__ inline void load_flags2(const int* p, int& a, int& b) {
  asm volatile(
    "global_load_dword %0, %2, off sc0 sc1\n\t"
    "global_load_dword %1, %2, off offset:256 sc0 sc1\n\t"
    "s_waitcnt vmcnt(0)"
    : "=&v"(a), "=&v"(b) : "v"(p) : "memory");
}
__device__ inline void store_h8_bypass(void* p, u64 v) {
  asm volatile("global_store_dwordx2 %0, %1, off sc0 sc1" :: "v"(p), "v"(v) : "memory");
}
__device__ inline void store_i32_bypass(int* p, int v) {
  asm volatile("global_store_dword %0, %1, off sc0 sc1" :: "v"(p), "v"(v) : "memory");
}
__device__ inline void wait_vm0() {
  asm volatile("s_waitcnt vmcnt(0)" ::: "memory");
}

// ---------------------------------------------------------------------------
// fp32 -> bf16 plain converter (for w_ih, layout preserved [g][e])
// ---------------------------------------------------------------------------
__global__ __launch_bounds__(256) void cvt_kernel(
    const float* __restrict__ src, __bf16* __restrict__ dst, int n8)
{
  int i = blockIdx.x * 256 + threadIdx.x;
  if (i >= n8) return;
  f32x4 a = *reinterpret_cast<const f32x4*>(src + 8 * (size_t)i);
  f32x4 b = *reinterpret_cast<const f32x4*>(src + 8 * (size_t)i + 4);
  bf16x8 o;
  o[0]=(__bf16)a[0]; o[1]=(__bf16)a[1]; o[2]=(__bf16)a[2]; o[3]=(__bf16)a[3];
  o[4]=(__bf16)b[0]; o[5]=(__bf16)b[1]; o[6]=(__bf16)b[2]; o[7]=(__bf16)b[3];
  *reinterpret_cast<bf16x8*>(dst + 8 * (size_t)i) = o;
}

// x: [b][s][e] fp32  ->  xb: [s][b][e] bf16 (transpose for contiguous GEMM rows)
__global__ __launch_bounds__(256) void cvt_x_kernel(
    const float* __restrict__ x, __bf16* __restrict__ xb)
{
  int i = blockIdx.x * 256 + threadIdx.x;           // i < 64*512*96
  int e8 = i % 96;
  int r  = i / 96;
  int b  = r & 63;
  int s  = r >> 6;
  const float* src = x + ((size_t)b * SS + s) * EMBD + e8 * 8;
  f32x4 a = *reinterpret_cast<const f32x4*>(src);
  f32x4 c = *reinterpret_cast<const f32x4*>(src + 4);
  bf16x8 o;
  o[0]=(__bf16)a[0]; o[1]=(__bf16)a[1]; o[2]=(__bf16)a[2]; o[3]=(__bf16)a[3];
  o[4]=(__bf16)c[0]; o[5]=(__bf16)c[1]; o[6]=(__bf16)c[2]; o[7]=(__bf16)c[3];
  *reinterpret_cast<bf16x8*>(xb + ((size_t)s * BB + b) * EMBD + e8 * 8) = o;
}

// ---------------------------------------------------------------------------
// Input projection, LDS-tiled bf16 MFMA GEMM (m97 pattern).
// Per WG: M=64 (batches), N=256 pcols, K=768 in 12 chunks of BK=64.
// A from xb [s][b][e] (rows contiguous); B rows = w_ih[g(pcol)][e].
// Epilogue writes xp[d][tt][pcol][b] fp32 (packed layout rec consumes):
//   g(p) = (p&3)*512 + 16*(p>>6) + 4*((p>>2)&3) + ((p>>4)&3)
// ---------------------------------------------------------------------------
__global__ __launch_bounds__(256, 2) void proj_kernel(
    const __bf16* __restrict__ xb, const __bf16* __restrict__ wfb,
    const __bf16* __restrict__ wbb, const float* __restrict__ bias_f,
    const float* __restrict__ bias_b, float* __restrict__ xp,
    int t0, int chunk)
{
  const int nb = blockIdx.x;                    // 8 blocks of 256 pcols
  const int tt = blockIdx.y;
  const int d  = blockIdx.z;
  const int s  = d ? (SS - 1 - (t0 + tt)) : (t0 + tt);
  const __bf16* __restrict__ wih  = d ? wbb : wfb;
  const float*  __restrict__ bias = d ? bias_b : bias_f;

  __shared__ __bf16 Asm[64 * 80];               // stride 80 elems (160B)
  __shared__ __bf16 Bsm[256 * 80];

  const int t    = threadIdx.x;
  const int wv   = t >> 6;
  const int l    = t & 63;
  const int quad = l >> 4;
  const int col  = l & 15;

  // bias per (j, col)
  float bj[4];
#pragma unroll
  for (int j = 0; j < 4; j++) {
    int p = 256 * nb + 64 * wv + 16 * j + col;
    int g = (p & 3) * HIDN + 16 * (p >> 6) + 4 * ((p >> 2) & 3) + ((p >> 4) & 3);
    bj[j] = bias[g];
  }

  f32x4 acc[4][4];
#pragma unroll
  for (int i = 0; i < 4; i++)
#pragma unroll
    for (int j = 0; j < 4; j++) acc[i][j] = f32x4{0.f, 0.f, 0.f, 0.f};

  const int r32 = t >> 3;                       // 0..31
  const int m8  = t & 7;
  const __bf16* xrow_base = xb + (size_t)s * BB * EMBD;

  for (int kc = 0; kc < 12; kc++) {
    const int k0 = kc * 64;
    __syncthreads();
    // stage A: 64 rows x 64 k
#pragma unroll
    for (int rr = 0; rr < 2; rr++) {
      int r = r32 + 32 * rr;
      *reinterpret_cast<bf16x8*>(Asm + r * 80 + m8 * 8) =
          *reinterpret_cast<const bf16x8*>(xrow_base + (size_t)r * EMBD + k0 + m8 * 8);
    }
    // stage B: 256 rows x 64 k
#pragma unroll
    for (int rr = 0; rr < 8; rr++) {
      int r = r32 + 32 * rr;
      int p = 256 * nb + r;
      int g = (p & 3) * HIDN + 16 * (p >> 6) + 4 * ((p >> 2) & 3) + ((p >> 4) & 3);
      *reinterpret_cast<bf16x8*>(Bsm + r * 80 + m8 * 8) =
          *reinterpret_cast<const bf16x8*>(wih + (size_t)g * EMBD + k0 + m8 * 8);
    }
    __syncthreads();
#pragma unroll
    for (int kkk = 0; kkk < 2; kkk++) {
      bf16x8 af[4], bf[4];
#pragma unroll
      for (int i = 0; i < 4; i++)
        af[i] = *reinterpret_cast<const bf16x8*>(Asm + (16 * i + col) * 80 + kkk * 32 + quad * 8);
#pragma unroll
      for (int j = 0; j < 4; j++)
        bf[j] = *reinterpret_cast<const bf16x8*>(Bsm + (64 * wv + 16 * j + col) * 80 + kkk * 32 + quad * 8);
#pragma unroll
      for (int i = 0; i < 4; i++)
#pragma unroll
        for (int j = 0; j < 4; j++)
          acc[i][j] = __builtin_amdgcn_mfma_f32_16x16x32_bf16(af[i], bf[j], acc[i][j], 0, 0, 0);
    }
  }
  float* xpd = xp + (size_t)(d * chunk + tt) * (size_t)G4 * BB;
#pragma unroll
  for (int i = 0; i < 4; i++)
#pragma unroll
    for (int j = 0; j < 4; j++) {
      int p = 256 * nb + 64 * wv + 16 * j + col;
      f32x4 v = acc[i][j];
      v[0] += bj[j]; v[1] += bj[j]; v[2] += bj[j]; v[3] += bj[j];
      *reinterpret_cast<f32x4*>(xpd + (size_t)p * BB + 16 * i + 4 * quad) = v;
    }
}

// ---------------------------------------------------------------------------
// Recurrence: cooperative, 64 WGs x 256 thr, ZERO intra-WG syncs.
// Per-wave flags (prog[d][sl*4+wv]); consumers poll all 128 flags in one
// pipelined 2-load round and process the 4 k-groups progressively.
// ---------------------------------------------------------------------------
struct RecCtl {
  int prog[2][128];
  int pad[64];
};

struct RecParams {
  const float* xp;       // [d][chunk][2048 packed][64] fp32
  const float* whh_f;    // [2048][512] fp32
  const float* whh_b;
  __bf16* hh;            // [d][chunk+1][64][512] bf16
  float*  cT;            // [d][512][64] fp32
  RecCtl* ctl;
  int     chunk;
};

__global__ __launch_bounds__(256, 1) void rec_kernel(RecParams p)
{
  const int wg   = blockIdx.x;
  const int d    = wg >> 5;
  const int sl   = wg & 31;
  const int t    = threadIdx.x;
  const int wv   = t >> 6;
  const int l    = t & 63;
  const int quad = l >> 4;
  const int col  = l & 15;
  const int hcl  = col >> 2;
  const int gate = col & 3;
  const int j4   = col & 3;

  const float* __restrict__ whh = d ? p.whh_b : p.whh_f;

  // Preload B fragments (bf16 w_hh) into registers
  bf16x8 bfrag[4][16];
#pragma unroll
  for (int j = 0; j < 4; j++) {
    const int hcb = 16 * sl + 4 * hcl + j;
    const float* wr = whh + (size_t)(gate * HIDN + hcb) * HIDN + 8 * quad;
#pragma unroll
    for (int kk = 0; kk < 16; kk++) {
      f32x4 w0 = *reinterpret_cast<const f32x4*>(wr + 32 * kk);
      f32x4 w1 = *reinterpret_cast<const f32x4*>(wr + 32 * kk + 4);
      bf16x8 v;
      v[0] = (__bf16)w0[0]; v[1] = (__bf16)w0[1]; v[2] = (__bf16)w0[2]; v[3] = (__bf16)w0[3];
      v[4] = (__bf16)w1[0]; v[5] = (__bf16)w1[1]; v[6] = (__bf16)w1[2]; v[7] = (__bf16)w1[3];
      bfrag[j][kk] = v;
    }
  }

  const int bA = 16 * wv + col;
  const int bC = 16 * wv + 4 * quad + gate;
  const int hcs = 16 * sl + 4 * hcl;
  const size_t slotsz = (size_t)BB * HIDN;
  __bf16* hhd = p.hh + (size_t)d * (p.chunk + 1) * slotsz;
  const float* xpd = p.xp + (size_t)d * p.chunk * ((size_t)G4 * BB);

  float c[4];
#pragma unroll
  for (int j = 0; j < 4; j++)
    c[j] = p.cT[((size_t)d * HIDN + hcs + j) * BB + bC];

  f32x4 xpn[4];
#pragma unroll
  for (int j = 0; j < 4; j++)
    xpn[j] = *reinterpret_cast<const f32x4*>(
        xpd + (size_t)(64 * sl + 16 * j + col) * BB + 16 * wv + 4 * quad);

  int* prog = &p.ctl->prog[d][0];
  const int* myflag = prog + l;          // fa = prog[l], fb = prog[64+l]
  int* ownflag = prog + sl * 4 + wv;

  u64 hword = 0;
  for (int tt = 0; tt < p.chunk; tt++) {
    const char* hbase = (const char*)hhd + (size_t)tt * slotsz * 2
                      + (size_t)bA * (HIDN * 2) + quad * 16;

    f32x4 acc[4][2];
#pragma unroll
    for (int j = 0; j < 4; j++) {
      acc[j][0] = xpn[j];
      acc[j][1] = f32x4{0.f, 0.f, 0.f, 0.f};
    }

    // progressive group consumption: group g = k in [128g, 128g+128)
    auto process_group = [&](int g) {
      f32x4 ar[4];
      load_h4_bypass(hbase + 256 * g, ar);
#pragma unroll
      for (int q = 0; q < 4; q++) {
        HCast hc_; hc_.f = ar[q];
        bf16x8 af = hc_.h;
        const int kk = 4 * g + q;
#pragma unroll
        for (int j = 0; j < 4; j++)
          acc[j][q & 1] = __builtin_amdgcn_mfma_f32_16x16x32_bf16(af, bfrag[j][kk], acc[j][q & 1], 0, 0, 0);
      }
    };

    if (tt == 0) {
      for (int g = 0; g < 4; g++) process_group(g);
    } else {
      int done = 0;
      while (done < 4) {
        int fa, fb;
        load_flags2(myflag, fa, fb);
        u64 ba = __ballot(fa >= tt);
        u64 bb = __ballot(fb >= tt);
        bool rdy[4] = { (ba & 0xffffffffull) == 0xffffffffull,
                        (ba >> 32)          == 0xffffffffull,
                        (bb & 0xffffffffull) == 0xffffffffull,
                        (bb >> 32)          == 0xffffffffull };
        bool prog_made = false;
        while (done < 4 && rdy[done]) { process_group(done); done++; prog_made = true; }
        if (done < 4 && !prog_made) __builtin_amdgcn_s_sleep(1);
      }
    }

    // cell update
    hword = 0;
#pragma unroll
    for (int j = 0; j < 4; j++) {
      float v0 = acc[j][0][0] + acc[j][1][0];
      float v1 = acc[j][0][1] + acc[j][1][1];
      float v2 = acc[j][0][2] + acc[j][1][2];
      float v3 = acc[j][0][3] + acc[j][1][3];
      {
        float t0 = __shfl_xor(v1, 1); float t1 = __shfl_xor(v0, 1);
        float t2 = __shfl_xor(v3, 1); float t3 = __shfl_xor(v2, 1);
        if (j4 & 1) { v0 = t0; v2 = t2; } else { v1 = t1; v3 = t3; }
        float u0 = __shfl_xor(v2, 2); float u1 = __shfl_xor(v3, 2);
        float u2 = __shfl_xor(v0, 2); float u3 = __shfl_xor(v1, 2);
        if (j4 & 2) { v0 = u0; v1 = u1; } else { v2 = u2; v3 = u3; }
      }
      float ig = 1.f / (1.f + __expf(-v0));
      float fg = 1.f / (1.f + __expf(-v1));
      float gg = 1.f - 2.f / (__expf(2.f * v2) + 1.f);
      float og = 1.f / (1.f + __expf(-v3));
      c[j] = fg * c[j] + ig * gg;
      float hn = og * (1.f - 2.f / (__expf(2.f * c[j]) + 1.f));
      union { __bf16 b; unsigned short u; } cv; cv.b = (__bf16)hn;
      hword |= (u64)cv.u << (16 * j);
    }
    store_h8_bypass((char*)hhd + (size_t)(tt + 1) * slotsz * 2
                    + (size_t)bC * (HIDN * 2) + (size_t)hcs * 2, hword);
    wait_vm0();                              // drain this wave's h stores
    if (l == 0) store_i32_bypass(ownflag, tt + 1);

    // xp prefetch for next step (completes during others' polls)
    if (tt + 1 < p.chunk) {
#pragma unroll
      for (int j = 0; j < 4; j++)
        xpn[j] = *reinterpret_cast<const f32x4*>(
            xpd + (size_t)(tt + 1) * ((size_t)G4 * BB)
            + (size_t)(64 * sl + 16 * j + col) * BB + 16 * wv + 4 * quad);
    }
  }

  // carry state to next chunk launch
  store_h8_bypass((char*)hhd + (size_t)bC * (HIDN * 2) + (size_t)hcs * 2, hword);
#pragma unroll
  for (int j = 0; j < 4; j++)
    p.cT[((size_t)d * HIDN + hcs + j) * BB + bC] = c[j];
}

// ---------------------------------------------------------------------------
__global__ __launch_bounds__(256) void emis_kernel(
    const __bf16* __restrict__ hh, const float* __restrict__ w_out,
    float* __restrict__ emis_f, float* __restrict__ emis_b,
    int t0, int chunk)
{
  const int tt = blockIdx.x;
  const int d  = blockIdx.y;
  const int t  = threadIdx.x;
  const int b  = t & 63;
  const int grp = t >> 6;

  const __bf16* hp = hh + ((size_t)d * (chunk + 1) + tt + 1) * ((size_t)BB * HIDN)
                   + (size_t)b * HIDN;
  const float* w0 = w_out + (size_t)grp * (2 * HIDN) + d * HIDN;
  const float* w1 = w_out + (size_t)(grp + 4) * (2 * HIDN) + d * HIDN;
  const float* w2 = w_out + (size_t)8 * (2 * HIDN) + d * HIDN;

  float a0 = 0.f, a1 = 0.f, a2 = 0.f;
  for (int k = 0; k < HIDN; k += 8) {
    bf16x8 hv8 = *reinterpret_cast<const bf16x8*>(hp + k);
#pragma unroll
    for (int j = 0; j < 8; j++) {
      float hv = (float)hv8[j];
      a0 += hv * w0[k + j];
      a1 += hv * w1[k + j];
      a2 += hv * w2[k + j];
    }
  }
  const int sidx = (d == 0) ? (t0 + tt) : (SS - 1 - (t0 + tt));
  float* dst = d ? emis_b : emis_f;
  dst[((size_t)sidx * BB + b) * NTAG + grp]     = a0;
  dst[((size_t)sidx * BB + b) * NTAG + grp + 4] = a1;
  if (grp == 0) dst[((size_t)sidx * BB + b) * NTAG + 8] = a2;
}

// ---------------------------------------------------------------------------
__global__ __launch_bounds__(64) void crf_kernel(
    const float* __restrict__ emis_f, const float* __restrict__ emis_b,
    const float* __restrict__ b_out, const float* __restrict__ start_tr,
    const float* __restrict__ end_tr, const float* __restrict__ trans,
    const int* __restrict__ mask, const int* __restrict__ target,
    float* __restrict__ llh)
{
  const int b    = blockIdx.x;
  const int lane = threadIdx.x;

  auto E = [&](int s, int tg) -> float {
    size_t o = ((size_t)s * BB + b) * NTAG + tg;
    return emis_f[o] + emis_b[o] + b_out[tg];
  };

  float numpart = 0.f;
  int msum = 0;
  for (int s = lane; s < SS; s += 64) {
    int m = mask[b * SS + s];
    msum += m;
    if (s >= 1 && m > 0) {
      int tp = target[b * SS + s - 1];
      int tc = target[b * SS + s];
      numpart += trans[tp * NTAG + tc] + E(s, tc);
    }
  }
#pragma unroll
  for (int off = 32; off > 0; off >>= 1) {
    numpart += __shfl_down(numpart, off, 64);
    msum    += __shfl_down(msum, off, 64);
  }

  const int tc = lane;
  const bool act = (tc < NTAG);
  float trc[NTAG] = {0.f};
  float alpha = 0.f;
  if (act) {
#pragma unroll
    for (int i = 0; i < NTAG; i++) trc[i] = trans[i * NTAG + tc];
    alpha = start_tr[tc] + E(0, tc);
  }
  for (int s = 1; s < SS; s++) {
    float e = act ? E(s, tc) : 0.f;
    float av[NTAG];
    float mx = -3.0e30f;
#pragma unroll
    for (int i = 0; i < NTAG; i++) {
      av[i] = __shfl(alpha, i, 64) + trc[i];
      mx = fmaxf(mx, av[i]);
    }
    float sum = 0.f;
#pragma unroll
    for (int i = 0; i < NTAG; i++) sum += __expf(av[i] - mx);
    float nxt = mx + __logf(sum) + e;
    if (act && mask[b * SS + s] > 0) alpha = nxt;
  }
  float fv = act ? (alpha + end_tr[tc]) : -3.0e30f;
  float q[NTAG];
  float mx2 = -3.0e30f;
#pragma unroll
  for (int i = 0; i < NTAG; i++) {
    q[i] = __shfl(fv, i, 64);
    mx2 = fmaxf(mx2, q[i]);
  }
  float s2 = 0.f;
#pragma unroll
  for (int i = 0; i < NTAG; i++) s2 += __expf(q[i] - mx2);
  float den = mx2 + __logf(s2);

  if (lane == 0) {
    int last = msum - 1;
    int tg0 = target[b * SS + 0];
    int tgl = target[b * SS + last];
    float num = start_tr[tg0] + E(0, tg0) + numpart + end_tr[tgl];
    llh[b] = num - den;
  }
}

__global__ __launch_bounds__(256) void fin_kernel(
    const float* __restrict__ llh, const int* __restrict__ mask,
    float* __restrict__ out)
{
  __shared__ float sf[256];
  __shared__ int   si[256];
  const int t = threadIdx.x;
  float a = (t < BB) ? llh[t] : 0.f;
  int m = 0;
  for (int i = t; i < BB * SS; i += 256) m += mask[i];
  sf[t] = a; si[t] = m;
  __syncthreads();
  for (int o = 128; o > 0; o >>= 1) {
    if (t < o) { sf[t] += sf[t + o]; si[t] += si[t + o]; }
    __syncthreads();
  }
  if (t == 0) out[0] = -(sf[0] / (float)si[0]);
}

// ---------------------------------------------------------------------------
extern "C" void kernel_launch(void* const* d_in, const int* in_sizes, int n_in,
                              void* d_out, int out_size, void* d_ws, size_t ws_size,
                              hipStream_t stream)
{
  const float* x     = (const float*)d_in[0];
  const int*   mask  = (const int*)d_in[1];
  const int*   targ  = (const int*)d_in[2];
  const float* wih_f = (const float*)d_in[3];
  const float* whh_f = (const float*)d_in[4];
  const float* b_f   = (const float*)d_in[5];
  const float* wih_b = (const float*)d_in[6];
  const float* whh_b = (const float*)d_in[7];
  const float* b_b   = (const float*)d_in[8];
  const float* w_out = (const float*)d_in[9];
  const float* b_out = (const float*)d_in[10];
  const float* st    = (const float*)d_in[11];
  const float* et    = (const float*)d_in[12];
  const float* tr    = (const float*)d_in[13];
  float* out = (float*)d_out;

  const size_t nxb   = (size_t)BB * SS * EMBD;       // x bf16 elements
  const size_t nwb   = (size_t)G4 * EMBD;            // w_ih bf16 elements (per dir)
  const size_t ctl_i = sizeof(RecCtl) / 4;
  const size_t fixed_f = (size_t)2 * SS * BB * NTAG + 64 + (size_t)2 * HIDN * BB
                       + ctl_i + nxb / 2 + nwb;
  int chunk = 1;
  for (int c = SS; c >= 1; c >>= 1) {
    size_t need = fixed_f * 4 + (size_t)c * 2 * G4 * BB * 4
                + (size_t)2 * (c + 1) * BB * HIDN * 2;
    if (need <= ws_size) { chunk = c; break; }
  }

  float* fp = (float*)d_ws;
  float* emis_f = fp; fp += (size_t)SS * BB * NTAG;
  float* emis_b = fp; fp += (size_t)SS * BB * NTAG;
  float* llh    = fp; fp += 64;
  float* cT     = fp; fp += (size_t)2 * HIDN * BB;
  RecCtl* ctl   = (RecCtl*)fp; fp += ctl_i;
  __bf16* xb16  = (__bf16*)fp; fp += nxb / 2;
  __bf16* wfb16 = (__bf16*)fp; fp += nwb / 2;
  __bf16* wbb16 = (__bf16*)fp; fp += nwb / 2;
  float* xp     = fp; fp += (size_t)chunk * 2 * G4 * BB;
  __bf16* hh    = (__bf16*)fp;

  // converts: x (with [s][b] transpose) + both w_ih
  {
    int nx8 = (int)(nxb / 8);
    cvt_x_kernel<<<dim3((nx8 + 255) / 256), 256, 0, stream>>>(x, xb16);
    int w8 = (int)(nwb / 8);
    cvt_kernel<<<dim3((w8 + 255) / 256), 256, 0, stream>>>(wih_f, wfb16, w8);
    cvt_kernel<<<dim3((w8 + 255) / 256), 256, 0, stream>>>(wih_b, wbb16, w8);
  }

  const size_t slotsz = (size_t)BB * HIDN;
  hipMemsetAsync(cT, 0, (size_t)2 * HIDN * BB * sizeof(float), stream);
  hipMemsetAsync(hh, 0, slotsz * sizeof(__bf16), stream);
  hipMemsetAsync(hh + (size_t)(chunk + 1) * slotsz, 0, slotsz * sizeof(__bf16), stream);

  const int nch = SS / chunk;
  for (int c = 0; c < nch; c++) {
    const int t0 = c * chunk;
    hipMemsetAsync(ctl, 0, sizeof(RecCtl), stream);
    proj_kernel<<<dim3(8, chunk, 2), 256, 0, stream>>>(
        xb16, wfb16, wbb16, b_f, b_b, xp, t0, chunk);
    RecParams rp{xp, whh_f, whh_b, hh, cT, ctl, chunk};
    void* ka[] = {&rp};
    hipLaunchCooperativeKernel(rec_kernel, dim3(64), dim3(256), ka, 0, stream);
    emis_kernel<<<dim3(chunk, 2), 256, 0, stream>>>(
        hh, w_out, emis_f, emis_b, t0, chunk);
  }
  crf_kernel<<<dim3(64), 64, 0, stream>>>(emis_f, emis_b, b_out, st, et, tr, mask, targ, llh);
  fin_kernel<<<dim3(1), 256, 0, stream>>>(llh, mask, out);
}